// Round 10
// baseline (272.308 us; speedup 1.0000x reference)
//
#include <hip/hip_runtime.h>
#include <hip/hip_fp16.h>
#include <cstdint>
#include <cstddef>

// Problem constants
#define NB 4
#define C 128
#define P 4096      // HR*WR
#define S 64
#define Q 4096      // HS*WS
#define WS_DIM 64
#define HS_DIM 64

#define PL   32     // p-rows per block
#define QTW  128    // q-tile width
#define NT   32     // q tiles (Q/QTW)
#define PITCH 136   // LDS row pitch in halfs (272B: 16B-aligned, quad-spread)

using half8 = __attribute__((ext_vector_type(8))) _Float16;
using f32x4 = __attribute__((ext_vector_type(4))) float;

// ws layout (halfs): fr_t [0, N*P*C) | fs_t [N*P*C, 2*N*P*C)  (8MB total)

// ---------- kernel 1: transpose-convert fr,fs -> pixel-major fp16 ----------
__global__ __launch_bounds__(256) void prep_h(
    const float* __restrict__ fr, const float* __restrict__ fs,
    __half* __restrict__ ws) {
  __shared__ float tile[32][65];
  int b = blockIdx.x;
  const float* src = (b < 1024) ? fr : fs;
  __half* dst = ws + ((b < 1024) ? 0 : (size_t)NB * P * C);
  int tb = b & 1023;
  int n  = tb >> 8;          // 256 tiles per batch
  int t  = tb & 255;
  int rti = t & 3;           // 4 row-tiles of 32 channels
  int cti = t >> 2;          // 64 col-tiles of 64 pixels
  int r0 = rti << 5, c0 = cti << 6;
  const float* Sp = src + (size_t)n * C * P;
  __half*      Dp = dst + (size_t)n * P * C;
  int tx = threadIdx.x & 15, ty = threadIdx.x >> 4;   // 16 x 16
#pragma unroll
  for (int i = 0; i < 2; ++i) {
    int row = ty + 16 * i;
    float4 v = *reinterpret_cast<const float4*>(
        &Sp[(size_t)(r0 + row) * P + c0 + tx * 4]);
    tile[row][tx * 4 + 0] = v.x;
    tile[row][tx * 4 + 1] = v.y;
    tile[row][tx * 4 + 2] = v.z;
    tile[row][tx * 4 + 3] = v.w;
  }
  __syncthreads();
  int ox = threadIdx.x & 7, oy = threadIdx.x >> 3;    // 8 x 32
#pragma unroll
  for (int i = 0; i < 2; ++i) {
    int prow = oy + 32 * i;
    __half2 h01 = __floats2half2_rn(tile[ox * 4 + 0][prow], tile[ox * 4 + 1][prow]);
    __half2 h23 = __floats2half2_rn(tile[ox * 4 + 2][prow], tile[ox * 4 + 3][prow]);
    uint2 pk;
    pk.x = *reinterpret_cast<unsigned int*>(&h01);
    pk.y = *reinterpret_cast<unsigned int*>(&h23);
    *reinterpret_cast<uint2*>(&Dp[(size_t)(c0 + prow) * C + r0 + ox * 4]) = pk;
  }
}

// ---------- kernel 2: fused corr-GEMM + bilinear gather --------------------
// Block = 32 p-rows x full q. Loop over 32 q-tiles of 128:
//   MFMA (K=128 one-shot, A frags hoisted in VGPRs) -> 32x128 corr subtile
//   -> fp16 to Cr_lds -> each thread accumulates its 8 samples' corner-pairs
//   that fall in this tile. corr never touches HBM.
// 4 waves: wave wv owns q-cols [wv*32, wv*32+32) (2x2 frags of 16x16), all p.
// C/D mapping (verified R9): col = lane&15, row = (lane>>4)*4 + reg.
__global__ __launch_bounds__(256) void fused_corr(
    const __half* __restrict__ ws,
    const float* __restrict__ grids, const float* __restrict__ mask,
    float* __restrict__ out, float* __restrict__ cmo) {
  const __half* fr_t = ws;
  const __half* fs_t = ws + (size_t)NB * P * C;
  __shared__ __half A_lds[PL][PITCH];
  __shared__ __half B_lds[QTW][PITCH];
  __shared__ __half Cr_lds[PL][PITCH];

  int b = blockIdx.x;              // [0,512)
  int xcd = b & 7;                 // XCD swizzle: 2 XCDs per batch
  int n = xcd >> 1;
  int pt = ((xcd & 1) << 6) | (b >> 3);   // [0,128)
  int p0 = pt << 5;
  int t = threadIdx.x;
  int lane = t & 63;
  int wv = t >> 6;
  int lm = lane & 15, kg = lane >> 4;
  int wn = wv * 32;
  int pl = t & 31, sg = t >> 5;
  int p = p0 + pl;

  // ---- issue A + B0 global loads ----
  uint4 areg[2];
  {
    int row = t >> 3, seg = t & 7;
    const uint4* src = reinterpret_cast<const uint4*>(
        fr_t + ((size_t)n * P + p0 + row) * C + seg * 16);
    areg[0] = src[0];
    areg[1] = src[1];
  }
  uint4 breg[8];
  {
    int row = t >> 1;
    const uint4* src = reinterpret_cast<const uint4*>(
        fs_t + ((size_t)n * Q + row) * C + (t & 1) * 64);
#pragma unroll
    for (int j = 0; j < 8; ++j) breg[j] = src[j];
  }

  // ---- per-thread sample precompute (overlaps load latency) ----
  // thread owns samples (p = p0 + pl, s = sg*8 + j), j = 0..7
  int   meta_[8];
  float w00_[8], w10_[8], w01_[8], w11_[8], cmm_[8], sacc[8];
#pragma unroll
  for (int j = 0; j < 8; ++j) {
    int s = sg * 8 + j;
    float gx = grids[(((size_t)n * S + s) * 2 + 0) * P + p];
    float gy = grids[(((size_t)n * S + s) * 2 + 1) * P + p];
    float mval = mask[((size_t)n * S + s) * P + p];
    float ix = gx - 0.5f, iy = gy - 0.5f;
    float x0f = floorf(ix), y0f = floorf(iy);
    float wx1 = ix - x0f, wy1 = iy - y0f;
    float wx0 = 1.0f - wx1, wy0 = 1.0f - wy1;
    int x0 = (int)x0f, y0 = (int)y0f;
    bool bx0 = (x0 >= 0) & (x0 < WS_DIM);
    bool bx1 = (x0 >= -1) & (x0 < WS_DIM - 1);   // x0+1 in bounds
    bool by0 = (y0 >= 0) & (y0 < HS_DIM);
    bool by1 = (y0 >= -1) & (y0 < HS_DIM - 1);   // y0+1 in bounds
    float w00 = (bx0 & by0) ? wx0 * wy0 : 0.0f;
    float w01 = (bx0 & by1) ? wx0 * wy1 : 0.0f;
    float w10 = (bx1 & by0) ? wx1 * wy0 : 0.0f;
    float w11 = (bx1 & by1) ? wx1 * wy1 : 0.0f;
    float msum = ((w00 + w01) + w10) + w11;      // reference order
    float cm = (msum < 0.9999f) ? 0.0f : 1.0f;
    float cmm = cm * mval;
    meta_[j] = (x0 + 1) | ((y0 + 1) << 8);       // both in [0,64]
    w00_[j] = w00; w10_[j] = w10; w01_[j] = w01; w11_[j] = w11;
    cmm_[j] = cmm;
    sacc[j] = 0.0f;
    cmo[((size_t)n * S + s) * P + p] = cmm;
  }

  // ---- LDS writes (padded pitch) ----
  {
    int row = t >> 3, seg = t & 7;
    uint4* d = reinterpret_cast<uint4*>(&A_lds[row][seg * 16]);
    d[0] = areg[0];
    d[1] = areg[1];
  }
  {
    int row = t >> 1;
    uint4* d = reinterpret_cast<uint4*>(&B_lds[row][(t & 1) * 64]);
#pragma unroll
    for (int j = 0; j < 8; ++j) d[j] = breg[j];
  }
  __syncthreads();

  // hoist A fragments for the whole kernel (rows = mf*16+lm, k contiguous)
  half8 afh[4][2];
#pragma unroll
  for (int ks = 0; ks < 4; ++ks)
#pragma unroll
    for (int mf = 0; mf < 2; ++mf)
      afh[ks][mf] = *reinterpret_cast<const half8*>(
          &A_lds[mf * 16 + lm][ks * 32 + kg * 8]);

#pragma unroll 1
  for (int qt = 0; qt < NT; ++qt) {
    // issue next B tile's global loads early (land at ds_write after barrier)
    if (qt + 1 < NT) {
      int row = t >> 1;
      const uint4* src = reinterpret_cast<const uint4*>(
          fs_t + ((size_t)n * Q + (qt + 1) * QTW + row) * C + (t & 1) * 64);
#pragma unroll
      for (int j = 0; j < 8; ++j) breg[j] = src[j];
    }
    __builtin_amdgcn_sched_barrier(0);   // pin load issue before MFMA phase

    f32x4 acc[2][2] = {};
#pragma unroll
    for (int ks = 0; ks < 4; ++ks) {
      half8 bf[2];
#pragma unroll
      for (int nf = 0; nf < 2; ++nf)
        bf[nf] = *reinterpret_cast<const half8*>(
            &B_lds[wn + nf * 16 + lm][ks * 32 + kg * 8]);
#pragma unroll
      for (int mf = 0; mf < 2; ++mf)
#pragma unroll
        for (int nf = 0; nf < 2; ++nf)
          acc[mf][nf] = __builtin_amdgcn_mfma_f32_16x16x32_f16(
              afh[ks][mf], bf[nf], acc[mf][nf], 0, 0, 0);
    }
    // corr subtile -> fp16 LDS (row = p_local, col = q_local)
#pragma unroll
    for (int mf = 0; mf < 2; ++mf)
#pragma unroll
      for (int nf = 0; nf < 2; ++nf)
#pragma unroll
        for (int r = 0; r < 4; ++r)
          Cr_lds[mf * 16 + kg * 4 + r][wn + nf * 16 + lm] =
              __float2half(acc[mf][nf][r]);
    __syncthreads();   // Cr ready; all waves done reading B_lds

    // stage next B tile into LDS (overlaps contrib phase below)
    if (qt + 1 < NT) {
      int row = t >> 1;
      uint4* d = reinterpret_cast<uint4*>(&B_lds[row][(t & 1) * 64]);
#pragma unroll
      for (int j = 0; j < 8; ++j) d[j] = breg[j];
    }

    // accumulate this tile's corner-pair contributions (from Cr_lds)
#pragma unroll
    for (int j = 0; j < 8; ++j) {
      int y0 = (meta_[j] >> 8) - 1;
      int x0 = (meta_[j] & 255) - 1;
      if ((y0 >> 1) == qt) {             // top pair (rows y0: w00,w10)
        int xl = ((y0 & 1) << 6) + x0;
        float v0 = __half2float(Cr_lds[pl][max(xl, 0)]);
        float v1 = __half2float(Cr_lds[pl][min(xl + 1, 127)]);
        sacc[j] += w00_[j] * v0 + w10_[j] * v1;
      }
      int y1 = y0 + 1;
      if ((y1 >> 1) == qt) {             // bottom pair (row y0+1: w01,w11)
        int xl = ((y1 & 1) << 6) + x0;
        float v0 = __half2float(Cr_lds[pl][max(xl, 0)]);
        float v1 = __half2float(Cr_lds[pl][min(xl + 1, 127)]);
        sacc[j] += w01_[j] * v0 + w11_[j] * v1;
      }
    }
    __syncthreads();   // contribs done before next Cr overwrite / B MFMA
  }

  // ---- epilogue: masked output ----
#pragma unroll
  for (int j = 0; j < 8; ++j) {
    int s = sg * 8 + j;
    out[((size_t)n * S + s) * P + p] = sacc[j] * cmm_[j];
  }
}

extern "C" void kernel_launch(void* const* d_in, const int* in_sizes, int n_in,
                              void* d_out, int out_size, void* d_ws, size_t ws_size,
                              hipStream_t stream) {
  const float* feat_ref = (const float*)d_in[0];  // (4,128,64,64)
  const float* feat_src = (const float*)d_in[1];  // (4,128,64,64)
  const float* grids    = (const float*)d_in[2];  // (4,64,2,64,64)
  const float* mask     = (const float*)d_in[3];  // (4,64,64,64)
  __half* ws = (__half*)d_ws;                     // needs 8MB
  float* out = (float*)d_out;                     // out: 1,048,576 floats
  float* cmo = out + (size_t)NB * S * P;          // then corr_mask

  prep_h<<<2048, 256, 0, stream>>>(feat_ref, feat_src, ws);
  fused_corr<<<512, 256, 0, stream>>>(ws, grids, mask, out, cmo);
}